// Round 20
// baseline (116.263 us; speedup 1.0000x reference)
//
#include <hip/hip_runtime.h>

using US   = unsigned short;
using bf8  = __attribute__((ext_vector_type(8))) __bf16;
using us8  = __attribute__((ext_vector_type(8))) US;
using us4  = __attribute__((ext_vector_type(4))) US;
using f4   = __attribute__((ext_vector_type(4))) float;
using f8   = __attribute__((ext_vector_type(8))) float;
using f16v = __attribute__((ext_vector_type(16))) float;
using i4   = __attribute__((ext_vector_type(4))) int;
using u2   = __attribute__((ext_vector_type(2))) unsigned;

__device__ __forceinline__ US f2bf(float x) {
  union { float f; unsigned u; } v; v.f = x;
  unsigned r = v.u + 0x7fffu + ((v.u >> 16) & 1u);
  return (US)(r >> 16);
}
__device__ __forceinline__ unsigned cvtpk(float a, float b) {
  unsigned r;
  asm("v_cvt_pk_bf16_f32 %0, %1, %2" : "=v"(r) : "v"(a), "v"(b));
  return r;
}
// raw v_exp_f32 (exp2): avoids the denormal-guard expansion of libm exp2f
#if __has_builtin(__builtin_amdgcn_exp2f)
__device__ __forceinline__ float ex2(float x) { return __builtin_amdgcn_exp2f(x); }
#else
__device__ __forceinline__ float ex2(float x) {
  float r;
  asm("v_exp_f32 %0, %1" : "=v"(r) : "v"(x));
  return r;
}
#endif
// async global->LDS, 16B/lane, linear LDS dest (wave-uniform base + lane*16)
__device__ __forceinline__ void gl16(const US* g, US* l) {
  __builtin_amdgcn_global_load_lds((const __attribute__((address_space(1))) void*)g,
                                   (__attribute__((address_space(3))) void*)l, 16, 0, 0);
}

// ---------- fused prologue: cvt(x) + transpose(Wqkv) + transpose(Wproj) -------
__global__ void prep_k(const float* __restrict__ x, US* __restrict__ xb,
                       const float* __restrict__ Wqkv, US* __restrict__ WqkvT,
                       const float* __restrict__ Wproj, US* __restrict__ WprojT) {
  __shared__ float tile[32][33];
  int bid = blockIdx.x;
  if (bid < 2048) {                     // cvt: x fp32 -> bf16, 8 elems/lane
    int i = bid * 256 + threadIdx.x;
    f8 v = ((const f8*)x)[i];
    us8 o;
#pragma unroll
    for (int j = 0; j < 8; ++j) o[j] = f2bf(v[j]);
    ((us8*)xb)[i] = o;
    return;
  }
  const float* in;
  US* out;
  int R, C, tx0, ty0;
  if (bid < 2048 + 3072) {              // Wqkv^T
    int tid = bid - 2048;
    in = Wqkv; out = WqkvT; R = 1024; C = 3072;
    tx0 = (tid % 96) * 32; ty0 = (tid / 96) * 32;
  } else {                              // Wproj^T
    int tid = bid - 2048 - 3072;
    in = Wproj; out = WprojT; R = 1024; C = 1024;
    tx0 = (tid % 32) * 32; ty0 = (tid / 32) * 32;
  }
  int tx = threadIdx.x & 31, ty = threadIdx.x >> 5;
  for (int i = ty; i < 32; i += 8)
    tile[i][tx] = in[(size_t)(ty0 + i) * C + tx0 + tx];
  __syncthreads();
  for (int i = ty; i < 32; i += 8)
    out[(size_t)(tx0 + i) * R + ty0 + tx] = f2bf(tile[tx][i]);
}

// 2-bit+2-bit XOR swizzle for BK=32 tiles
__device__ __forceinline__ int SW4(int row) { return (row & 3) ^ ((row >> 2) & 3); }

// ---------- C[M,N] = A[M,K](bf16) * Bt[N,K](bf16)^T + bias(f32) ----------
// counted-vmcnt protocol, now 2-AHEAD: prologue stages tiles 0,1; per iter:
// vmcnt(4) [t landed, t+1 in flight] -> barrier -> STAGE(t+2) -> compute(t).
// Stage(t+2) writes buffer (t-1)%3 whose reads finished before barrier(t)
// (MFMA consumption forces ds_read completion) -> race-free.
template <typename OT, bool QSC = false, bool VT = false>
__global__ __launch_bounds__(256, 2) void gemm_ct(const US* __restrict__ A,
                                                  const US* __restrict__ Bt,
                                                  const float* __restrict__ bias,
                                                  OT* __restrict__ out,
                                                  US* __restrict__ vtout,
                                                  int M, int N, int K) {
  __shared__ US lA[3][128 * 32];        // 3 x 8 KB
  __shared__ US lB[3][128 * 32];        // 3 x 8 KB
  const int t = threadIdx.x;
  const int lane = t & 63;
  const int w = t >> 6;
  const int wr = w >> 1, wc = w & 1;
  const int l15 = lane & 15, g = lane >> 4;
  const int m0 = blockIdx.x * 128, n0 = blockIdx.y * 128;

  float bv[4];
#pragma unroll
  for (int ni = 0; ni < 4; ++ni)
    bv[ni] = bias ? bias[n0 + wc * 64 + ni * 16 + l15] : 0.0f;

  const int r16 = lane >> 2;
  const int u4 = lane & 3;
  const int csw = (u4 ^ SW4(r16)) * 8;

#define GSTAGE(buf, k0s)                                                          \
  {                                                                               \
    _Pragma("unroll") for (int s = 0; s < 2; ++s) {                               \
      const int rb = w * 32 + s * 16;                                             \
      gl16(A + (size_t)(m0 + rb + r16) * K + (k0s) + csw, &lA[buf][rb * 32]);     \
      gl16(Bt + (size_t)(n0 + rb + r16) * K + (k0s) + csw, &lB[buf][rb * 32]);    \
    }                                                                             \
  }

  const int kk = K >> 5;
  GSTAGE(0, 0);
  if (kk > 1) GSTAGE(1, 32);

  f4 acc[4][4] = {};
  int cur = 0;
  for (int tt = 0; tt < kk; ++tt) {
    if (tt + 1 < kk) {
      asm volatile("s_waitcnt vmcnt(4)" ::: "memory");  // t landed, t+1 in flight
    } else {
      asm volatile("s_waitcnt vmcnt(0)" ::: "memory");
    }
    __builtin_amdgcn_s_barrier();
    asm volatile("" ::: "memory");
    if (tt + 2 < kk) {
      int nb = cur + 2; if (nb >= 3) nb -= 3;
      GSTAGE(nb, (tt + 2) * 32);        // issued under compute(t): ~2 iters slack
    }

    const US* a_ = lA[cur];
    const US* b_ = lB[cur];
    bf8 af[4], bfr[4];
#pragma unroll
    for (int mi = 0; mi < 4; ++mi) {
      int row = wr * 64 + mi * 16 + l15;
      af[mi] = *(const bf8*)((const char*)a_ + row * 64 + ((g ^ SW4(row)) << 4));
    }
#pragma unroll
    for (int ni = 0; ni < 4; ++ni) {
      int row = wc * 64 + ni * 16 + l15;
      bfr[ni] = *(const bf8*)((const char*)b_ + row * 64 + ((g ^ SW4(row)) << 4));
    }
    __builtin_amdgcn_s_setprio(1);
#pragma unroll
    for (int mi = 0; mi < 4; ++mi)
#pragma unroll
      for (int ni = 0; ni < 4; ++ni)
        acc[mi][ni] = __builtin_amdgcn_mfma_f32_16x16x32_bf16(af[mi], bfr[ni], acc[mi][ni], 0, 0, 0);
    __builtin_amdgcn_s_setprio(0);
    cur = cur + 1 == 3 ? 0 : cur + 1;
  }
#undef GSTAGE

  if (VT && n0 >= 2048) {
#pragma unroll
    for (int ni = 0; ni < 4; ++ni) {
      int cv = n0 - 2048 + wc * 64 + ni * 16 + l15;
      int h2 = cv >> 6, d = cv & 63;
#pragma unroll
      for (int mi = 0; mi < 4; ++mi) {
        int rowb = m0 + wr * 64 + mi * 16 + g * 4;
        int bb = rowb >> 11, tloc = rowb & 2047;
        us4 pk;
#pragma unroll
        for (int r = 0; r < 4; ++r) pk[r] = f2bf(acc[mi][ni][r] + bv[ni]);
        *(us4*)(vtout + ((size_t)(bb * 16 + h2) * 64 + d) * 2048 + tloc) = pk;
      }
    }
    return;
  }
  const float oscale = (QSC && n0 < 1024) ? 0.18033688011f : 1.0f;
#pragma unroll
  for (int ni = 0; ni < 4; ++ni) {
    int col = n0 + wc * 64 + ni * 16 + l15;
#pragma unroll
    for (int mi = 0; mi < 4; ++mi) {
      int rowb = m0 + wr * 64 + mi * 16 + g * 4;
#pragma unroll
      for (int r = 0; r < 4; ++r) {
        float val = (acc[mi][ni][r] + bv[ni]) * oscale;
        if constexpr (sizeof(OT) == 2)
          out[(size_t)(rowb + r) * N + col] = f2bf(val);
        else
          out[(size_t)(rowb + r) * N + col] = val;
      }
    }
  }
}

// swizzled LDS fragment read: row r, 16B unit u = 2*ks+hi, byte = r*128 + ((u^(r&7))<<4)
__device__ __forceinline__ const bf8* fragp(const US* base, int r, int ks, int hi) {
  int byte = r * 128 + ((((ks << 1) | hi) ^ (r & 7)) << 4);
  return (const bf8*)((const char*)base + byte);
}

// ---------- flash attention: 4 waves x 32 q-rows, K/V quad-buffer, T15 pipe ----
// r16 structure with the 2-AHEAD staging variant: prologue stages 0,1; per
// iter: vmcnt(4) -> barrier -> STAGE(t+2). Stage(t+2) writes buffer (t-2)&3:
// its K reads happened in iter t-2, V reads in PV(t-2) during iter t-1 --
// both complete before barrier(t). Quad buffer remains necessary for T15.
__global__ __launch_bounds__(256, 2) void attn_k(const US* __restrict__ qkv,
                                                 const US* __restrict__ vt,
                                                 const int* __restrict__ mask,
                                                 US* __restrict__ y) {
  int f0 = blockIdx.x;                  // 0..511
  int f = ((f0 & 7) << 6) | (f0 >> 3);  // XCD bijective remap (512 = 8*64)
  const int qt = f & 15;                // 16 q-tiles of 128 rows
  const int bh = f >> 4;                // 0..31
  const int b = bh >> 4;
  const int h = bh & 15;
  const int lane = threadIdx.x & 63, w = threadIdx.x >> 6;
  const int l31 = lane & 31, hi = lane >> 5;

  __shared__ US lK[4][64 * 64];         // 32 KB
  __shared__ US lV[4][64 * 64];         // 32 KB
  __shared__ unsigned char lMaskB[256]; // 2048 mask bits

  const int qr0 = qt * 128 + w * 32;
  const US* qrow = qkv + (size_t)(b * 2048 + qr0 + l31) * 3072 + h * 64 + hi * 8;
  bf8 qf[4];
#pragma unroll
  for (int ks = 0; ks < 4; ++ks) qf[ks] = *(const bf8*)(qrow + ks * 16);

  const int r8 = lane >> 3;
  const int c16 = (lane & 7) ^ r8;
  const US* kg = qkv + (size_t)b * 2048 * 3072 + 1024 + h * 64 + c16 * 8;
  const US* vg = vt + (size_t)bh * 64 * 2048 + c16 * 8;
  const int R0 = w * 16;

  f16v o0 = {}, o1 = {};
  f16v osum = {};
  bf8 pf[4] = {};
  bf8 ones;
  {
    union { US u[8]; bf8 v; } on;
#pragma unroll
    for (int i = 0; i < 8; ++i) on.u[i] = 0x3F80;
    ones = on.v;
  }

#define STAGE(buf, j0s)                                                        \
  {                                                                            \
    gl16(kg + (size_t)((j0s) + R0 + r8) * 3072, &lK[buf][R0 * 64]);            \
    gl16(kg + (size_t)((j0s) + R0 + 8 + r8) * 3072, &lK[buf][(R0 + 8) * 64]);  \
    gl16(vg + (size_t)(R0 + r8) * 2048 + (j0s), &lV[buf][R0 * 64]);            \
    gl16(vg + (size_t)(R0 + 8 + r8) * 2048 + (j0s), &lV[buf][(R0 + 8) * 64]);  \
  }

  STAGE(0, 0);

  // prologue: mask -> 256B LDS bitmask (drains vmcnt once, before the loop)
  int allones;
  {
    const int t8 = threadIdx.x * 8;
    i4 ma = *(const i4*)(mask + b * 2048 + t8);
    i4 mc = *(const i4*)(mask + b * 2048 + t8 + 4);
    unsigned byte = 0;
#pragma unroll
    for (int k = 0; k < 4; ++k) {
      byte |= (ma[k] != 0 ? 1u : 0u) << k;
      byte |= (mc[k] != 0 ? 1u : 0u) << (k + 4);
    }
    lMaskB[threadIdx.x] = (unsigned char)byte;
    allones = __syncthreads_and((int)(byte == 0xFFu));
  }
  STAGE(1, 64);                         // second tile in flight

#pragma unroll 4
  for (int tt = 0; tt < 32; ++tt) {
    const int cur = tt & 3;
    const int j0 = tt * 64;
    if (tt < 31) {
      asm volatile("s_waitcnt vmcnt(4)" ::: "memory");  // t landed, t+1 in flight
    } else {
      asm volatile("s_waitcnt vmcnt(0)" ::: "memory");
    }
    __builtin_amdgcn_s_barrier();
    asm volatile("" ::: "memory");
    if (tt + 2 < 32) STAGE((tt + 2) & 3, j0 + 128);

    const US* lKc = lK[cur];

    f16v s0 = {}, s1 = {};
    __builtin_amdgcn_s_setprio(1);
#pragma unroll
    for (int ks = 0; ks < 4; ++ks) {
      bf8 ka0 = *fragp(lKc, l31, ks, hi);
      bf8 ka1 = *fragp(lKc, 32 + l31, ks, hi);
      s0 = __builtin_amdgcn_mfma_f32_32x32x16_bf16(ka0, qf[ks], s0, 0, 0, 0);
      s1 = __builtin_amdgcn_mfma_f32_32x32x16_bf16(ka1, qf[ks], s1, 0, 0, 0);
    }
    if (tt) {
      const US* lVp = lV[(tt + 3) & 3];
#pragma unroll
      for (int ks = 0; ks < 4; ++ks) {
        bf8 vf0 = *fragp(lVp, l31, ks, hi);
        bf8 vf1 = *fragp(lVp, 32 + l31, ks, hi);
        o0 = __builtin_amdgcn_mfma_f32_32x32x16_bf16(vf0, pf[ks], o0, 0, 0, 0);
        o1 = __builtin_amdgcn_mfma_f32_32x32x16_bf16(vf1, pf[ks], o1, 0, 0, 0);
        osum = __builtin_amdgcn_mfma_f32_32x32x16_bf16(ones, pf[ks], osum, 0, 0, 0);
      }
    }
    __builtin_amdgcn_s_setprio(0);

#pragma unroll
    for (int i = 0; i < 16; ++i) {
      s0[i] = ex2(s0[i]);
      s1[i] = ex2(s1[i]);
    }
    if (!allones) {
      unsigned mbyte = lMaskB[(j0 >> 3) + (lane >> 3)];
      int mword = (mbyte >> (lane & 7)) & 1;
      unsigned long long mbits = __ballot(mword != 0);
#pragma unroll
      for (int i = 0; i < 16; ++i) {
        int r = (i & 3) + 8 * (i >> 2) + 4 * hi;
        if (!((mbits >> r) & 1)) s0[i] = 0.0f;
        if (!((mbits >> (32 + r)) & 1)) s1[i] = 0.0f;
      }
    }

#pragma unroll
    for (int ks = 0; ks < 4; ++ks) {
      const f16v& st = (ks < 2) ? s0 : s1;
      const int R = (ks & 1) * 8;
      unsigned w0 = cvtpk(st[R + 0], st[R + 1]);
      unsigned w1 = cvtpk(st[R + 2], st[R + 3]);
      unsigned w2 = cvtpk(st[R + 4], st[R + 5]);
      unsigned w3 = cvtpk(st[R + 6], st[R + 7]);
      u2 p02 = __builtin_amdgcn_permlane32_swap(w0, w2, false, false);
      u2 p13 = __builtin_amdgcn_permlane32_swap(w1, w3, false, false);
      union { unsigned u[4]; bf8 v; } bld;
      bld.u[0] = p02[0];
      bld.u[1] = p13[0];
      bld.u[2] = p02[1];
      bld.u[3] = p13[1];
      pf[ks] = bld.v;
    }
  }
#undef STAGE

  {
    const US* lVp = lV[3];
    __builtin_amdgcn_s_setprio(1);
#pragma unroll
    for (int ks = 0; ks < 4; ++ks) {
      bf8 vf0 = *fragp(lVp, l31, ks, hi);
      bf8 vf1 = *fragp(lVp, 32 + l31, ks, hi);
      o0 = __builtin_amdgcn_mfma_f32_32x32x16_bf16(vf0, pf[ks], o0, 0, 0, 0);
      o1 = __builtin_amdgcn_mfma_f32_32x32x16_bf16(vf1, pf[ks], o1, 0, 0, 0);
      osum = __builtin_amdgcn_mfma_f32_32x32x16_bf16(ones, pf[ks], osum, 0, 0, 0);
    }
    __builtin_amdgcn_s_setprio(0);
  }

  float inv = 1.0f / osum[0];
  US* yrow = y + (size_t)(b * 2048 + qr0 + l31) * 1024 + h * 64;
#pragma unroll
  for (int qd = 0; qd < 4; ++qd) {
    us4 pk0, pk1;
#pragma unroll
    for (int j = 0; j < 4; ++j) {
      pk0[j] = f2bf(o0[qd * 4 + j] * inv);
      pk1[j] = f2bf(o1[qd * 4 + j] * inv);
    }
    *(us4*)(yrow + qd * 8 + hi * 4) = pk0;
    *(us4*)(yrow + 32 + qd * 8 + hi * 4) = pk1;
  }
}

extern "C" void kernel_launch(void* const* d_in, const int* in_sizes, int n_in,
                              void* d_out, int out_size, void* d_ws, size_t ws_size,
                              hipStream_t stream) {
  const float* x     = (const float*)d_in[0];
  const int*   mask  = (const int*)d_in[1];
  const float* Wqkv  = (const float*)d_in[2];
  const float* bqkv  = (const float*)d_in[3];
  const float* Wproj = (const float*)d_in[4];
  const float* bproj = (const float*)d_in[5];
  float* out = (float*)d_out;

  US* xb     = (US*)d_ws;                        // 4096*1024
  US* qkvb   = xb     + (size_t)4096 * 1024;     // 4096*3072 (V region unused)
  US* WqkvT  = qkvb   + (size_t)4096 * 3072;     // 3072*1024
  US* WprojT = WqkvT  + (size_t)3072 * 1024;     // 1024*1024
  US* Vt     = WprojT + (size_t)1024 * 1024;     // 32*64*2048
  US* yb     = Vt     + (size_t)32 * 64 * 2048;  // 4096*1024

  prep_k<<<6144, 256, 0, stream>>>(x, xb, Wqkv, WqkvT, Wproj, WprojT);
  gemm_ct<US, true, true><<<dim3(32, 24), 256, 0, stream>>>(xb, WqkvT, bqkv, qkvb, Vt, 4096, 3072, 1024);
  attn_k<<<512, 256, 0, stream>>>(qkvb, Vt, mask, yb);
  gemm_ct<float><<<dim3(32, 8), 256, 0, stream>>>(yb, WprojT, bproj, out, nullptr, 4096, 1024, 1024);
}

// Round 21
// 108.649 us; speedup vs baseline: 1.0701x; 1.0701x over previous
//
#include <hip/hip_runtime.h>

using US   = unsigned short;
using bf8  = __attribute__((ext_vector_type(8))) __bf16;
using us8  = __attribute__((ext_vector_type(8))) US;
using us4  = __attribute__((ext_vector_type(4))) US;
using f4   = __attribute__((ext_vector_type(4))) float;
using f8   = __attribute__((ext_vector_type(8))) float;
using f16v = __attribute__((ext_vector_type(16))) float;
using i4   = __attribute__((ext_vector_type(4))) int;
using u2   = __attribute__((ext_vector_type(2))) unsigned;

__device__ __forceinline__ US f2bf(float x) {
  union { float f; unsigned u; } v; v.f = x;
  unsigned r = v.u + 0x7fffu + ((v.u >> 16) & 1u);
  return (US)(r >> 16);
}
__device__ __forceinline__ unsigned cvtpk(float a, float b) {
  unsigned r;
  asm("v_cvt_pk_bf16_f32 %0, %1, %2" : "=v"(r) : "v"(a), "v"(b));
  return r;
}
// raw v_exp_f32 (exp2): avoids the denormal-guard expansion of libm exp2f
#if __has_builtin(__builtin_amdgcn_exp2f)
__device__ __forceinline__ float ex2(float x) { return __builtin_amdgcn_exp2f(x); }
#else
__device__ __forceinline__ float ex2(float x) {
  float r;
  asm("v_exp_f32 %0, %1" : "=v"(r) : "v"(x));
  return r;
}
#endif
// async global->LDS, 16B/lane, linear LDS dest (wave-uniform base + lane*16)
__device__ __forceinline__ void gl16(const US* g, US* l) {
  __builtin_amdgcn_global_load_lds((const __attribute__((address_space(1))) void*)g,
                                   (__attribute__((address_space(3))) void*)l, 16, 0, 0);
}

// ---------- fused prologue: cvt(x) + transpose(Wqkv) + transpose(Wproj) -------
__global__ void prep_k(const float* __restrict__ x, US* __restrict__ xb,
                       const float* __restrict__ Wqkv, US* __restrict__ WqkvT,
                       const float* __restrict__ Wproj, US* __restrict__ WprojT) {
  __shared__ float tile[32][33];
  int bid = blockIdx.x;
  if (bid < 2048) {                     // cvt: x fp32 -> bf16, 8 elems/lane
    int i = bid * 256 + threadIdx.x;
    f8 v = ((const f8*)x)[i];
    us8 o;
#pragma unroll
    for (int j = 0; j < 8; ++j) o[j] = f2bf(v[j]);
    ((us8*)xb)[i] = o;
    return;
  }
  const float* in;
  US* out;
  int R, C, tx0, ty0;
  if (bid < 2048 + 3072) {              // Wqkv^T
    int tid = bid - 2048;
    in = Wqkv; out = WqkvT; R = 1024; C = 3072;
    tx0 = (tid % 96) * 32; ty0 = (tid / 96) * 32;
  } else {                              // Wproj^T
    int tid = bid - 2048 - 3072;
    in = Wproj; out = WprojT; R = 1024; C = 1024;
    tx0 = (tid % 32) * 32; ty0 = (tid / 32) * 32;
  }
  int tx = threadIdx.x & 31, ty = threadIdx.x >> 5;
  for (int i = ty; i < 32; i += 8)
    tile[i][tx] = in[(size_t)(ty0 + i) * C + tx0 + tx];
  __syncthreads();
  for (int i = ty; i < 32; i += 8)
    out[(size_t)(tx0 + i) * R + ty0 + tx] = f2bf(tile[tx][i]);
}

// 2-bit+2-bit XOR swizzle for BK=32 tiles
__device__ __forceinline__ int SW4(int row) { return (row & 3) ^ ((row >> 2) & 3); }

// ---------- C[M,N] = A[M,K](bf16) * Bt[N,K](bf16)^T + bias(f32) ----------
// (r19-verified 1-ahead counted-vmcnt protocol) BK=32, triple-buffered gl16
// staging, ONE barrier per K-step. NREP: N sub-tiles per wave (4 -> BN=128,
// 2 -> BN=64). NREP=2 halves the block's N-extent so small-N GEMMs (proj:
// N=1024) get 512 blocks -> 2 blocks/CU instead of a 1-block/CU grid cap.
template <typename OT, bool QSC = false, bool VT = false, int NREP = 4>
__global__ __launch_bounds__(256, 2) void gemm_ct(const US* __restrict__ A,
                                                  const US* __restrict__ Bt,
                                                  const float* __restrict__ bias,
                                                  OT* __restrict__ out,
                                                  US* __restrict__ vtout,
                                                  int M, int N, int K) {
  __shared__ US lA[3][128 * 32];            // 3 x 8 KB
  __shared__ US lB[3][NREP * 32 * 32];      // 3 x (BN x 32)
  const int t = threadIdx.x;
  const int lane = t & 63;
  const int w = t >> 6;
  const int wr = w >> 1, wc = w & 1;
  const int l15 = lane & 15, g = lane >> 4;
  const int m0 = blockIdx.x * 128, n0 = blockIdx.y * (NREP * 32);

  float bv[NREP];
#pragma unroll
  for (int ni = 0; ni < NREP; ++ni)
    bv[ni] = bias ? bias[n0 + wc * (NREP * 16) + ni * 16 + l15] : 0.0f;

  const int r16 = lane >> 2;
  const int u4 = lane & 3;
  const int csw = (u4 ^ SW4(r16)) * 8;

#define GSTAGE(buf, k0s)                                                          \
  {                                                                               \
    _Pragma("unroll") for (int s = 0; s < 2; ++s) {                               \
      const int rb = w * 32 + s * 16;                                             \
      gl16(A + (size_t)(m0 + rb + r16) * K + (k0s) + csw, &lA[buf][rb * 32]);     \
    }                                                                             \
    _Pragma("unroll") for (int s = 0; s < NREP / 2; ++s) {                        \
      const int rb = w * (8 * NREP) + s * 16;                                     \
      gl16(Bt + (size_t)(n0 + rb + r16) * K + (k0s) + csw, &lB[buf][rb * 32]);    \
    }                                                                             \
  }

  GSTAGE(0, 0);

  f4 acc[4][NREP] = {};
  const int kk = K >> 5;
  int cur = 0;
  for (int tt = 0; tt < kk; ++tt) {
    if (tt + 1 < kk) {
      int nb = cur + 1; if (nb == 3) nb = 0;
      GSTAGE(nb, (tt + 1) * 32);
      if constexpr (NREP == 4)
        asm volatile("s_waitcnt vmcnt(4)" ::: "memory");
      else
        asm volatile("s_waitcnt vmcnt(3)" ::: "memory");
    } else {
      asm volatile("s_waitcnt vmcnt(0)" ::: "memory");
    }
    __builtin_amdgcn_s_barrier();
    asm volatile("" ::: "memory");

    const US* a_ = lA[cur];
    const US* b_ = lB[cur];
    bf8 af[4], bfr[NREP];
#pragma unroll
    for (int mi = 0; mi < 4; ++mi) {
      int row = wr * 64 + mi * 16 + l15;
      af[mi] = *(const bf8*)((const char*)a_ + row * 64 + ((g ^ SW4(row)) << 4));
    }
#pragma unroll
    for (int ni = 0; ni < NREP; ++ni) {
      int row = wc * (NREP * 16) + ni * 16 + l15;
      bfr[ni] = *(const bf8*)((const char*)b_ + row * 64 + ((g ^ SW4(row)) << 4));
    }
    __builtin_amdgcn_s_setprio(1);
#pragma unroll
    for (int mi = 0; mi < 4; ++mi)
#pragma unroll
      for (int ni = 0; ni < NREP; ++ni)
        acc[mi][ni] = __builtin_amdgcn_mfma_f32_16x16x32_bf16(af[mi], bfr[ni], acc[mi][ni], 0, 0, 0);
    __builtin_amdgcn_s_setprio(0);
    cur = cur + 1 == 3 ? 0 : cur + 1;
  }
#undef GSTAGE

  if constexpr (VT) {
    if (n0 >= 2048) {                   // V region: write transposed to Vt only
#pragma unroll
      for (int ni = 0; ni < NREP; ++ni) {
        int cv = n0 - 2048 + wc * (NREP * 16) + ni * 16 + l15;
        int h2 = cv >> 6, d = cv & 63;
#pragma unroll
        for (int mi = 0; mi < 4; ++mi) {
          int rowb = m0 + wr * 64 + mi * 16 + g * 4;
          int bb = rowb >> 11, tloc = rowb & 2047;
          us4 pk;
#pragma unroll
          for (int r = 0; r < 4; ++r) pk[r] = f2bf(acc[mi][ni][r] + bv[ni]);
          *(us4*)(vtout + ((size_t)(bb * 16 + h2) * 64 + d) * 2048 + tloc) = pk;
        }
      }
      return;
    }
  }
  const float oscale = (QSC && n0 < 1024) ? 0.18033688011f : 1.0f;
#pragma unroll
  for (int ni = 0; ni < NREP; ++ni) {
    int col = n0 + wc * (NREP * 16) + ni * 16 + l15;
#pragma unroll
    for (int mi = 0; mi < 4; ++mi) {
      int rowb = m0 + wr * 64 + mi * 16 + g * 4;
#pragma unroll
      for (int r = 0; r < 4; ++r) {
        float val = (acc[mi][ni][r] + bv[ni]) * oscale;
        if constexpr (sizeof(OT) == 2)
          out[(size_t)(rowb + r) * N + col] = f2bf(val);
        else
          out[(size_t)(rowb + r) * N + col] = val;
      }
    }
  }
}

// swizzled LDS fragment read: row r, 16B unit u = 2*ks+hi, byte = r*128 + ((u^(r&7))<<4)
__device__ __forceinline__ const bf8* fragp(const US* base, int r, int ks, int hi) {
  int byte = r * 128 + ((((ks << 1) | hi) ^ (r & 7)) << 4);
  return (const bf8*)((const char*)base + byte);
}

// ---------- flash attention: 4 waves x 32 q-rows, K/V quad-buffer, T15 pipe ----
// (r19-verified version, 48.2 us: 1-ahead counted vmcnt(4), pure-gl16 vmcnt
// domain, mask = 256B LDS bitmask + all-ones fast path, Q pre-scaled in qkv
// GEMM, raw v_exp_f32, ones-MFMA row-sum, x4-unrolled loop.)
__global__ __launch_bounds__(256, 2) void attn_k(const US* __restrict__ qkv,
                                                 const US* __restrict__ vt,
                                                 const int* __restrict__ mask,
                                                 US* __restrict__ y) {
  int f0 = blockIdx.x;                  // 0..511
  int f = ((f0 & 7) << 6) | (f0 >> 3);  // XCD bijective remap (512 = 8*64)
  const int qt = f & 15;                // 16 q-tiles of 128 rows
  const int bh = f >> 4;                // 0..31
  const int b = bh >> 4;
  const int h = bh & 15;
  const int lane = threadIdx.x & 63, w = threadIdx.x >> 6;
  const int l31 = lane & 31, hi = lane >> 5;

  __shared__ US lK[4][64 * 64];         // 32 KB
  __shared__ US lV[4][64 * 64];         // 32 KB
  __shared__ unsigned char lMaskB[256]; // 2048 mask bits

  const int qr0 = qt * 128 + w * 32;
  const US* qrow = qkv + (size_t)(b * 2048 + qr0 + l31) * 3072 + h * 64 + hi * 8;
  bf8 qf[4];
#pragma unroll
  for (int ks = 0; ks < 4; ++ks) qf[ks] = *(const bf8*)(qrow + ks * 16);

  const int r8 = lane >> 3;
  const int c16 = (lane & 7) ^ r8;
  const US* kg = qkv + (size_t)b * 2048 * 3072 + 1024 + h * 64 + c16 * 8;
  const US* vg = vt + (size_t)bh * 64 * 2048 + c16 * 8;
  const int R0 = w * 16;

  f16v o0 = {}, o1 = {};
  f16v osum = {};
  bf8 pf[4] = {};
  bf8 ones;
  {
    union { US u[8]; bf8 v; } on;
#pragma unroll
    for (int i = 0; i < 8; ++i) on.u[i] = 0x3F80;
    ones = on.v;
  }

#define STAGE(buf, j0s)                                                        \
  {                                                                            \
    gl16(kg + (size_t)((j0s) + R0 + r8) * 3072, &lK[buf][R0 * 64]);            \
    gl16(kg + (size_t)((j0s) + R0 + 8 + r8) * 3072, &lK[buf][(R0 + 8) * 64]);  \
    gl16(vg + (size_t)(R0 + r8) * 2048 + (j0s), &lV[buf][R0 * 64]);            \
    gl16(vg + (size_t)(R0 + 8 + r8) * 2048 + (j0s), &lV[buf][(R0 + 8) * 64]);  \
  }

  STAGE(0, 0);

  int allones;
  {
    const int t8 = threadIdx.x * 8;
    i4 ma = *(const i4*)(mask + b * 2048 + t8);
    i4 mc = *(const i4*)(mask + b * 2048 + t8 + 4);
    unsigned byte = 0;
#pragma unroll
    for (int k = 0; k < 4; ++k) {
      byte |= (ma[k] != 0 ? 1u : 0u) << k;
      byte |= (mc[k] != 0 ? 1u : 0u) << (k + 4);
    }
    lMaskB[threadIdx.x] = (unsigned char)byte;
    allones = __syncthreads_and((int)(byte == 0xFFu));
  }

#pragma unroll 4
  for (int tt = 0; tt < 32; ++tt) {
    const int cur = tt & 3;
    const int j0 = tt * 64;
    if (tt < 31) {
      STAGE((tt + 1) & 3, j0 + 64);
      asm volatile("s_waitcnt vmcnt(4)" ::: "memory");
    } else {
      asm volatile("s_waitcnt vmcnt(0)" ::: "memory");
    }
    __builtin_amdgcn_s_barrier();
    asm volatile("" ::: "memory");

    const US* lKc = lK[cur];

    f16v s0 = {}, s1 = {};
    __builtin_amdgcn_s_setprio(1);
#pragma unroll
    for (int ks = 0; ks < 4; ++ks) {
      bf8 ka0 = *fragp(lKc, l31, ks, hi);
      bf8 ka1 = *fragp(lKc, 32 + l31, ks, hi);
      s0 = __builtin_amdgcn_mfma_f32_32x32x16_bf16(ka0, qf[ks], s0, 0, 0, 0);
      s1 = __builtin_amdgcn_mfma_f32_32x32x16_bf16(ka1, qf[ks], s1, 0, 0, 0);
    }
    if (tt) {
      const US* lVp = lV[(tt + 3) & 3];
#pragma unroll
      for (int ks = 0; ks < 4; ++ks) {
        bf8 vf0 = *fragp(lVp, l31, ks, hi);
        bf8 vf1 = *fragp(lVp, 32 + l31, ks, hi);
        o0 = __builtin_amdgcn_mfma_f32_32x32x16_bf16(vf0, pf[ks], o0, 0, 0, 0);
        o1 = __builtin_amdgcn_mfma_f32_32x32x16_bf16(vf1, pf[ks], o1, 0, 0, 0);
        osum = __builtin_amdgcn_mfma_f32_32x32x16_bf16(ones, pf[ks], osum, 0, 0, 0);
      }
    }
    __builtin_amdgcn_s_setprio(0);

#pragma unroll
    for (int i = 0; i < 16; ++i) {
      s0[i] = ex2(s0[i]);
      s1[i] = ex2(s1[i]);
    }
    if (!allones) {
      unsigned mbyte = lMaskB[(j0 >> 3) + (lane >> 3)];
      int mword = (mbyte >> (lane & 7)) & 1;
      unsigned long long mbits = __ballot(mword != 0);
#pragma unroll
      for (int i = 0; i < 16; ++i) {
        int r = (i & 3) + 8 * (i >> 2) + 4 * hi;
        if (!((mbits >> r) & 1)) s0[i] = 0.0f;
        if (!((mbits >> (32 + r)) & 1)) s1[i] = 0.0f;
      }
    }

#pragma unroll
    for (int ks = 0; ks < 4; ++ks) {
      const f16v& st = (ks < 2) ? s0 : s1;
      const int R = (ks & 1) * 8;
      unsigned w0 = cvtpk(st[R + 0], st[R + 1]);
      unsigned w1 = cvtpk(st[R + 2], st[R + 3]);
      unsigned w2 = cvtpk(st[R + 4], st[R + 5]);
      unsigned w3 = cvtpk(st[R + 6], st[R + 7]);
      u2 p02 = __builtin_amdgcn_permlane32_swap(w0, w2, false, false);
      u2 p13 = __builtin_amdgcn_permlane32_swap(w1, w3, false, false);
      union { unsigned u[4]; bf8 v; } bld;
      bld.u[0] = p02[0];
      bld.u[1] = p13[0];
      bld.u[2] = p02[1];
      bld.u[3] = p13[1];
      pf[ks] = bld.v;
    }
  }
#undef STAGE

  {
    const US* lVp = lV[3];
    __builtin_amdgcn_s_setprio(1);
#pragma unroll
    for (int ks = 0; ks < 4; ++ks) {
      bf8 vf0 = *fragp(lVp, l31, ks, hi);
      bf8 vf1 = *fragp(lVp, 32 + l31, ks, hi);
      o0 = __builtin_amdgcn_mfma_f32_32x32x16_bf16(vf0, pf[ks], o0, 0, 0, 0);
      o1 = __builtin_amdgcn_mfma_f32_32x32x16_bf16(vf1, pf[ks], o1, 0, 0, 0);
      osum = __builtin_amdgcn_mfma_f32_32x32x16_bf16(ones, pf[ks], osum, 0, 0, 0);
    }
    __builtin_amdgcn_s_setprio(0);
  }

  float inv = 1.0f / osum[0];
  US* yrow = y + (size_t)(b * 2048 + qr0 + l31) * 1024 + h * 64;
#pragma unroll
  for (int qd = 0; qd < 4; ++qd) {
    us4 pk0, pk1;
#pragma unroll
    for (int j = 0; j < 4; ++j) {
      pk0[j] = f2bf(o0[qd * 4 + j] * inv);
      pk1[j] = f2bf(o1[qd * 4 + j] * inv);
    }
    *(us4*)(yrow + qd * 8 + hi * 4) = pk0;
    *(us4*)(yrow + 32 + qd * 8 + hi * 4) = pk1;
  }
}

extern "C" void kernel_launch(void* const* d_in, const int* in_sizes, int n_in,
                              void* d_out, int out_size, void* d_ws, size_t ws_size,
                              hipStream_t stream) {
  const float* x     = (const float*)d_in[0];
  const int*   mask  = (const int*)d_in[1];
  const float* Wqkv  = (const float*)d_in[2];
  const float* bqkv  = (const float*)d_in[3];
  const float* Wproj = (const float*)d_in[4];
  const float* bproj = (const float*)d_in[5];
  float* out = (float*)d_out;

  US* xb     = (US*)d_ws;                        // 4096*1024
  US* qkvb   = xb     + (size_t)4096 * 1024;     // 4096*3072 (V region unused)
  US* WqkvT  = qkvb   + (size_t)4096 * 3072;     // 3072*1024
  US* WprojT = WqkvT  + (size_t)3072 * 1024;     // 1024*1024
  US* Vt     = WprojT + (size_t)1024 * 1024;     // 32*64*2048
  US* yb     = Vt     + (size_t)32 * 64 * 2048;  // 4096*1024

  prep_k<<<6144, 256, 0, stream>>>(x, xb, Wqkv, WqkvT, Wproj, WprojT);
  gemm_ct<US, true, true, 4><<<dim3(32, 24), 256, 0, stream>>>(xb, WqkvT, bqkv, qkvb, Vt, 4096, 3072, 1024);
  attn_k<<<512, 256, 0, stream>>>(qkvb, Vt, mask, yb);
  gemm_ct<float, false, false, 2><<<dim3(32, 16), 256, 0, stream>>>(yb, WprojT, bproj, out, nullptr, 4096, 1024, 1024);
}

// Round 22
// 107.258 us; speedup vs baseline: 1.0840x; 1.0130x over previous
//
#include <hip/hip_runtime.h>

using US   = unsigned short;
using bf8  = __attribute__((ext_vector_type(8))) __bf16;
using us8  = __attribute__((ext_vector_type(8))) US;
using us4  = __attribute__((ext_vector_type(4))) US;
using f4   = __attribute__((ext_vector_type(4))) float;
using f8   = __attribute__((ext_vector_type(8))) float;
using f16v = __attribute__((ext_vector_type(16))) float;
using i4   = __attribute__((ext_vector_type(4))) int;
using u2   = __attribute__((ext_vector_type(2))) unsigned;

__device__ __forceinline__ US f2bf(float x) {
  union { float f; unsigned u; } v; v.f = x;
  unsigned r = v.u + 0x7fffu + ((v.u >> 16) & 1u);
  return (US)(r >> 16);
}
__device__ __forceinline__ unsigned cvtpk(float a, float b) {
  unsigned r;
  asm("v_cvt_pk_bf16_f32 %0, %1, %2" : "=v"(r) : "v"(a), "v"(b));
  return r;
}
// raw v_exp_f32 (exp2): avoids the denormal-guard expansion of libm exp2f
#if __has_builtin(__builtin_amdgcn_exp2f)
__device__ __forceinline__ float ex2(float x) { return __builtin_amdgcn_exp2f(x); }
#else
__device__ __forceinline__ float ex2(float x) {
  float r;
  asm("v_exp_f32 %0, %1" : "=v"(r) : "v"(x));
  return r;
}
#endif
// async global->LDS, 16B/lane, linear LDS dest (wave-uniform base + lane*16)
__device__ __forceinline__ void gl16(const US* g, US* l) {
  __builtin_amdgcn_global_load_lds((const __attribute__((address_space(1))) void*)g,
                                   (__attribute__((address_space(3))) void*)l, 16, 0, 0);
}

// ---------- fused prologue: cvt(x) + transpose(Wqkv) + transpose(Wproj) -------
__global__ void prep_k(const float* __restrict__ x, US* __restrict__ xb,
                       const float* __restrict__ Wqkv, US* __restrict__ WqkvT,
                       const float* __restrict__ Wproj, US* __restrict__ WprojT) {
  __shared__ float tile[32][33];
  int bid = blockIdx.x;
  if (bid < 2048) {                     // cvt: x fp32 -> bf16, 8 elems/lane
    int i = bid * 256 + threadIdx.x;
    f8 v = ((const f8*)x)[i];
    us8 o;
#pragma unroll
    for (int j = 0; j < 8; ++j) o[j] = f2bf(v[j]);
    ((us8*)xb)[i] = o;
    return;
  }
  const float* in;
  US* out;
  int R, C, tx0, ty0;
  if (bid < 2048 + 3072) {              // Wqkv^T
    int tid = bid - 2048;
    in = Wqkv; out = WqkvT; R = 1024; C = 3072;
    tx0 = (tid % 96) * 32; ty0 = (tid / 96) * 32;
  } else {                              // Wproj^T
    int tid = bid - 2048 - 3072;
    in = Wproj; out = WprojT; R = 1024; C = 1024;
    tx0 = (tid % 32) * 32; ty0 = (tid / 32) * 32;
  }
  int tx = threadIdx.x & 31, ty = threadIdx.x >> 5;
  for (int i = ty; i < 32; i += 8)
    tile[i][tx] = in[(size_t)(ty0 + i) * C + tx0 + tx];
  __syncthreads();
  for (int i = ty; i < 32; i += 8)
    out[(size_t)(tx0 + i) * R + ty0 + tx] = f2bf(tile[tx][i]);
}

// 2-bit+2-bit XOR swizzle for BK=32 tiles
__device__ __forceinline__ int SW4(int row) { return (row & 3) ^ ((row >> 2) & 3); }

// ---------- C[M,N] = A[M,K](bf16) * Bt[N,K](bf16)^T + bias(f32) ----------
// r19-verified 1-ahead counted-vmcnt protocol (BK=32, triple-buffered gl16,
// ONE barrier per K-step) with two additions:
//  (a) XCD m-slice ownership: 1-D grid, id=(xcd,s); each XCD owns 4 contiguous
//      m-rows -> its A-slice (1 MB) is L2-resident while B streams (T1).
//  (b) K-loop hand-unrolled period-3 (K=1024 fixed -> 32 steps = 10x3+2) so
//      all LDS buffer bases are compile-time immediates.
// NREP: N sub-tiles per wave (4 -> BN=128, 2 -> BN=64 for small-N grids).
template <typename OT, bool QSC = false, bool VT = false, int NREP = 4>
__global__ __launch_bounds__(256, 2) void gemm_ct(const US* __restrict__ A,
                                                  const US* __restrict__ Bt,
                                                  const float* __restrict__ bias,
                                                  OT* __restrict__ out,
                                                  US* __restrict__ vtout,
                                                  int M, int N, int K) {
  __shared__ US lA[3][128 * 32];            // 3 x 8 KB
  __shared__ US lB[3][NREP * 32 * 32];      // 3 x (BN x 32)
  const int t = threadIdx.x;
  const int lane = t & 63;
  const int w = t >> 6;
  const int wr = w >> 1, wc = w & 1;
  const int l15 = lane & 15, g = lane >> 4;
  // XCD m-slice remap: M=4096 -> 32 m-blocks -> 4 per XCD
  const int id = blockIdx.x;
  const int xcd = id & 7;
  const int s = id >> 3;
  const int m0 = (xcd * 4 + (s & 3)) * 128;
  const int n0 = (s >> 2) * (NREP * 32);

  float bv[NREP];
#pragma unroll
  for (int ni = 0; ni < NREP; ++ni)
    bv[ni] = bias ? bias[n0 + wc * (NREP * 16) + ni * 16 + l15] : 0.0f;

  const int r16 = lane >> 2;
  const int u4 = lane & 3;
  const int csw = (u4 ^ SW4(r16)) * 8;

#define GSTAGE(buf, k0s)                                                          \
  {                                                                               \
    _Pragma("unroll") for (int ss = 0; ss < 2; ++ss) {                            \
      const int rb = w * 32 + ss * 16;                                            \
      gl16(A + (size_t)(m0 + rb + r16) * K + (k0s) + csw, &lA[buf][rb * 32]);     \
    }                                                                             \
    _Pragma("unroll") for (int ss = 0; ss < NREP / 2; ++ss) {                     \
      const int rb = w * (8 * NREP) + ss * 16;                                    \
      gl16(Bt + (size_t)(n0 + rb + r16) * K + (k0s) + csw, &lB[buf][rb * 32]);    \
    }                                                                             \
  }

  GSTAGE(0, 0);

  f4 acc[4][NREP] = {};

#define GTILE(tt, CUR, NXT, LAST)                                              \
  {                                                                            \
    if (!(LAST)) {                                                             \
      GSTAGE(NXT, ((tt) + 1) * 32);                                            \
      if constexpr (NREP == 4)                                                 \
        asm volatile("s_waitcnt vmcnt(4)" ::: "memory");                       \
      else                                                                     \
        asm volatile("s_waitcnt vmcnt(3)" ::: "memory");                       \
    } else {                                                                   \
      asm volatile("s_waitcnt vmcnt(0)" ::: "memory");                         \
    }                                                                          \
    __builtin_amdgcn_s_barrier();                                              \
    asm volatile("" ::: "memory");                                             \
    const US* a_ = lA[CUR];                                                    \
    const US* b_ = lB[CUR];                                                    \
    bf8 af[4], bfr[NREP];                                                      \
    _Pragma("unroll") for (int mi = 0; mi < 4; ++mi) {                         \
      int row = wr * 64 + mi * 16 + l15;                                       \
      af[mi] = *(const bf8*)((const char*)a_ + row * 64 + ((g ^ SW4(row)) << 4)); \
    }                                                                          \
    _Pragma("unroll") for (int ni = 0; ni < NREP; ++ni) {                      \
      int row = wc * (NREP * 16) + ni * 16 + l15;                              \
      bfr[ni] = *(const bf8*)((const char*)b_ + row * 64 + ((g ^ SW4(row)) << 4)); \
    }                                                                          \
    __builtin_amdgcn_s_setprio(1);                                             \
    _Pragma("unroll") for (int mi = 0; mi < 4; ++mi)                           \
      _Pragma("unroll") for (int ni = 0; ni < NREP; ++ni)                      \
        acc[mi][ni] = __builtin_amdgcn_mfma_f32_16x16x32_bf16(af[mi], bfr[ni], acc[mi][ni], 0, 0, 0); \
    __builtin_amdgcn_s_setprio(0);                                             \
  }

  // K = 1024 fixed -> 32 K-steps, period-3 static rotation
  for (int gg = 0; gg < 10; ++gg) {
    const int t3 = gg * 3;
    GTILE(t3, 0, 1, 0)
    GTILE(t3 + 1, 1, 2, 0)
    GTILE(t3 + 2, 2, 0, 0)
  }
  GTILE(30, 0, 1, 0)
  GTILE(31, 1, 2, 1)
#undef GTILE
#undef GSTAGE

  if constexpr (VT) {
    if (n0 >= 2048) {                   // V region: write transposed to Vt only
#pragma unroll
      for (int ni = 0; ni < NREP; ++ni) {
        int cv = n0 - 2048 + wc * (NREP * 16) + ni * 16 + l15;
        int h2 = cv >> 6, d = cv & 63;
#pragma unroll
        for (int mi = 0; mi < 4; ++mi) {
          int rowb = m0 + wr * 64 + mi * 16 + g * 4;
          int bb = rowb >> 11, tloc = rowb & 2047;
          us4 pk;
#pragma unroll
          for (int r = 0; r < 4; ++r) pk[r] = f2bf(acc[mi][ni][r] + bv[ni]);
          *(us4*)(vtout + ((size_t)(bb * 16 + h2) * 64 + d) * 2048 + tloc) = pk;
        }
      }
      return;
    }
  }
  const float oscale = (QSC && n0 < 1024) ? 0.18033688011f : 1.0f;
#pragma unroll
  for (int ni = 0; ni < NREP; ++ni) {
    int col = n0 + wc * (NREP * 16) + ni * 16 + l15;
#pragma unroll
    for (int mi = 0; mi < 4; ++mi) {
      int rowb = m0 + wr * 64 + mi * 16 + g * 4;
#pragma unroll
      for (int r = 0; r < 4; ++r) {
        float val = (acc[mi][ni][r] + bv[ni]) * oscale;
        if constexpr (sizeof(OT) == 2)
          out[(size_t)(rowb + r) * N + col] = f2bf(val);
        else
          out[(size_t)(rowb + r) * N + col] = val;
      }
    }
  }
}

// swizzled LDS fragment read: row r, 16B unit u = 2*ks+hi, byte = r*128 + ((u^(r&7))<<4)
__device__ __forceinline__ const bf8* fragp(const US* base, int r, int ks, int hi) {
  int byte = r * 128 + ((((ks << 1) | hi) ^ (r & 7)) << 4);
  return (const bf8*)((const char*)base + byte);
}

// ---------- flash attention: 4 waves x 32 q-rows, K/V quad-buffer, T15 pipe ----
// (frozen r19/r21 version, 48.2 us verified)
__global__ __launch_bounds__(256, 2) void attn_k(const US* __restrict__ qkv,
                                                 const US* __restrict__ vt,
                                                 const int* __restrict__ mask,
                                                 US* __restrict__ y) {
  int f0 = blockIdx.x;                  // 0..511
  int f = ((f0 & 7) << 6) | (f0 >> 3);  // XCD bijective remap (512 = 8*64)
  const int qt = f & 15;                // 16 q-tiles of 128 rows
  const int bh = f >> 4;                // 0..31
  const int b = bh >> 4;
  const int h = bh & 15;
  const int lane = threadIdx.x & 63, w = threadIdx.x >> 6;
  const int l31 = lane & 31, hi = lane >> 5;

  __shared__ US lK[4][64 * 64];         // 32 KB
  __shared__ US lV[4][64 * 64];         // 32 KB
  __shared__ unsigned char lMaskB[256]; // 2048 mask bits

  const int qr0 = qt * 128 + w * 32;
  const US* qrow = qkv + (size_t)(b * 2048 + qr0 + l31) * 3072 + h * 64 + hi * 8;
  bf8 qf[4];
#pragma unroll
  for (int ks = 0; ks < 4; ++ks) qf[ks] = *(const bf8*)(qrow + ks * 16);

  const int r8 = lane >> 3;
  const int c16 = (lane & 7) ^ r8;
  const US* kg = qkv + (size_t)b * 2048 * 3072 + 1024 + h * 64 + c16 * 8;
  const US* vg = vt + (size_t)bh * 64 * 2048 + c16 * 8;
  const int R0 = w * 16;

  f16v o0 = {}, o1 = {};
  f16v osum = {};
  bf8 pf[4] = {};
  bf8 ones;
  {
    union { US u[8]; bf8 v; } on;
#pragma unroll
    for (int i = 0; i < 8; ++i) on.u[i] = 0x3F80;
    ones = on.v;
  }

#define STAGE(buf, j0s)                                                        \
  {                                                                            \
    gl16(kg + (size_t)((j0s) + R0 + r8) * 3072, &lK[buf][R0 * 64]);            \
    gl16(kg + (size_t)((j0s) + R0 + 8 + r8) * 3072, &lK[buf][(R0 + 8) * 64]);  \
    gl16(vg + (size_t)(R0 + r8) * 2048 + (j0s), &lV[buf][R0 * 64]);            \
    gl16(vg + (size_t)(R0 + 8 + r8) * 2048 + (j0s), &lV[buf][(R0 + 8) * 64]);  \
  }

  STAGE(0, 0);

  int allones;
  {
    const int t8 = threadIdx.x * 8;
    i4 ma = *(const i4*)(mask + b * 2048 + t8);
    i4 mc = *(const i4*)(mask + b * 2048 + t8 + 4);
    unsigned byte = 0;
#pragma unroll
    for (int k = 0; k < 4; ++k) {
      byte |= (ma[k] != 0 ? 1u : 0u) << k;
      byte |= (mc[k] != 0 ? 1u : 0u) << (k + 4);
    }
    lMaskB[threadIdx.x] = (unsigned char)byte;
    allones = __syncthreads_and((int)(byte == 0xFFu));
  }

#pragma unroll 4
  for (int tt = 0; tt < 32; ++tt) {
    const int cur = tt & 3;
    const int j0 = tt * 64;
    if (tt < 31) {
      STAGE((tt + 1) & 3, j0 + 64);
      asm volatile("s_waitcnt vmcnt(4)" ::: "memory");
    } else {
      asm volatile("s_waitcnt vmcnt(0)" ::: "memory");
    }
    __builtin_amdgcn_s_barrier();
    asm volatile("" ::: "memory");

    const US* lKc = lK[cur];

    f16v s0 = {}, s1 = {};
    __builtin_amdgcn_s_setprio(1);
#pragma unroll
    for (int ks = 0; ks < 4; ++ks) {
      bf8 ka0 = *fragp(lKc, l31, ks, hi);
      bf8 ka1 = *fragp(lKc, 32 + l31, ks, hi);
      s0 = __builtin_amdgcn_mfma_f32_32x32x16_bf16(ka0, qf[ks], s0, 0, 0, 0);
      s1 = __builtin_amdgcn_mfma_f32_32x32x16_bf16(ka1, qf[ks], s1, 0, 0, 0);
    }
    if (tt) {
      const US* lVp = lV[(tt + 3) & 3];
#pragma unroll
      for (int ks = 0; ks < 4; ++ks) {
        bf8 vf0 = *fragp(lVp, l31, ks, hi);
        bf8 vf1 = *fragp(lVp, 32 + l31, ks, hi);
        o0 = __builtin_amdgcn_mfma_f32_32x32x16_bf16(vf0, pf[ks], o0, 0, 0, 0);
        o1 = __builtin_amdgcn_mfma_f32_32x32x16_bf16(vf1, pf[ks], o1, 0, 0, 0);
        osum = __builtin_amdgcn_mfma_f32_32x32x16_bf16(ones, pf[ks], osum, 0, 0, 0);
      }
    }
    __builtin_amdgcn_s_setprio(0);

#pragma unroll
    for (int i = 0; i < 16; ++i) {
      s0[i] = ex2(s0[i]);
      s1[i] = ex2(s1[i]);
    }
    if (!allones) {
      unsigned mbyte = lMaskB[(j0 >> 3) + (lane >> 3)];
      int mword = (mbyte >> (lane & 7)) & 1;
      unsigned long long mbits = __ballot(mword != 0);
#pragma unroll
      for (int i = 0; i < 16; ++i) {
        int r = (i & 3) + 8 * (i >> 2) + 4 * hi;
        if (!((mbits >> r) & 1)) s0[i] = 0.0f;
        if (!((mbits >> (32 + r)) & 1)) s1[i] = 0.0f;
      }
    }

#pragma unroll
    for (int ks = 0; ks < 4; ++ks) {
      const f16v& st = (ks < 2) ? s0 : s1;
      const int R = (ks & 1) * 8;
      unsigned w0 = cvtpk(st[R + 0], st[R + 1]);
      unsigned w1 = cvtpk(st[R + 2], st[R + 3]);
      unsigned w2 = cvtpk(st[R + 4], st[R + 5]);
      unsigned w3 = cvtpk(st[R + 6], st[R + 7]);
      u2 p02 = __builtin_amdgcn_permlane32_swap(w0, w2, false, false);
      u2 p13 = __builtin_amdgcn_permlane32_swap(w1, w3, false, false);
      union { unsigned u[4]; bf8 v; } bld;
      bld.u[0] = p02[0];
      bld.u[1] = p13[0];
      bld.u[2] = p02[1];
      bld.u[3] = p13[1];
      pf[ks] = bld.v;
    }
  }
#undef STAGE

  {
    const US* lVp = lV[3];
    __builtin_amdgcn_s_setprio(1);
#pragma unroll
    for (int ks = 0; ks < 4; ++ks) {
      bf8 vf0 = *fragp(lVp, l31, ks, hi);
      bf8 vf1 = *fragp(lVp, 32 + l31, ks, hi);
      o0 = __builtin_amdgcn_mfma_f32_32x32x16_bf16(vf0, pf[ks], o0, 0, 0, 0);
      o1 = __builtin_amdgcn_mfma_f32_32x32x16_bf16(vf1, pf[ks], o1, 0, 0, 0);
      osum = __builtin_amdgcn_mfma_f32_32x32x16_bf16(ones, pf[ks], osum, 0, 0, 0);
    }
    __builtin_amdgcn_s_setprio(0);
  }

  float inv = 1.0f / osum[0];
  US* yrow = y + (size_t)(b * 2048 + qr0 + l31) * 1024 + h * 64;
#pragma unroll
  for (int qd = 0; qd < 4; ++qd) {
    us4 pk0, pk1;
#pragma unroll
    for (int j = 0; j < 4; ++j) {
      pk0[j] = f2bf(o0[qd * 4 + j] * inv);
      pk1[j] = f2bf(o1[qd * 4 + j] * inv);
    }
    *(us4*)(yrow + qd * 8 + hi * 4) = pk0;
    *(us4*)(yrow + 32 + qd * 8 + hi * 4) = pk1;
  }
}

extern "C" void kernel_launch(void* const* d_in, const int* in_sizes, int n_in,
                              void* d_out, int out_size, void* d_ws, size_t ws_size,
                              hipStream_t stream) {
  const float* x     = (const float*)d_in[0];
  const int*   mask  = (const int*)d_in[1];
  const float* Wqkv  = (const float*)d_in[2];
  const float* bqkv  = (const float*)d_in[3];
  const float* Wproj = (const float*)d_in[4];
  const float* bproj = (const float*)d_in[5];
  float* out = (float*)d_out;

  US* xb     = (US*)d_ws;                        // 4096*1024
  US* qkvb   = xb     + (size_t)4096 * 1024;     // 4096*3072 (V region unused)
  US* WqkvT  = qkvb   + (size_t)4096 * 3072;     // 3072*1024
  US* WprojT = WqkvT  + (size_t)3072 * 1024;     // 1024*1024
  US* Vt     = WprojT + (size_t)1024 * 1024;     // 32*64*2048
  US* yb     = Vt     + (size_t)32 * 64 * 2048;  // 4096*1024

  prep_k<<<6144, 256, 0, stream>>>(x, xb, Wqkv, WqkvT, Wproj, WprojT);
  gemm_ct<US, true, true, 4><<<768, 256, 0, stream>>>(xb, WqkvT, bqkv, qkvb, Vt, 4096, 3072, 1024);
  attn_k<<<512, 256, 0, stream>>>(qkvb, Vt, mask, yb);
  gemm_ct<float, false, false, 2><<<512, 256, 0, stream>>>(yb, WprojT, bproj, out, nullptr, 4096, 1024, 1024);
}